// Round 12
// baseline (231.871 us; speedup 1.0000x reference)
//
#include <hip/hip_runtime.h>
#include <hip/hip_bf16.h>

#define T_N 256
#define B_N 32
#define D_N 512
#define H_N 8
#define HD_N 64
#define ETA_N 4
#define R_N 4
#define FEAT_N 256
#define NCOL 2688            // 5*512 + 3*32 = 2656, padded to 21*128
#define TB_N (T_N * B_N)     // 8192
#define NCHUNK 32
#define CLEN 8               // T / NCHUNK

using bf16 = __hip_bfloat16;
typedef __attribute__((ext_vector_type(8))) short short8;
typedef __attribute__((ext_vector_type(4))) float f32x4;
typedef __attribute__((ext_vector_type(4))) unsigned short u16x4;

__device__ __forceinline__ float sigmoidf_(float x) { return 1.f / (1.f + __expf(-x)); }
__device__ __forceinline__ float b2f(unsigned short u) {
  union { unsigned int i; float f; } x; x.i = ((unsigned int)u) << 16; return x.f;
}

// ---------------- fused prep: cast x -> Xb, cast Wo -> Wob, build Wcat ----------------
// blocks [0,4096): x cast (4 f32/thr). [4096,4352): Wo cast. [4352,9728): wcat (1 elem/thr).
__global__ __launch_bounds__(256) void prep_all(
    const float* __restrict__ x, const float* __restrict__ Wo,
    const float* __restrict__ Wq, const float* __restrict__ Wk,
    const float* __restrict__ Wv, const float* __restrict__ Wb,
    const float* __restrict__ Wg, const float* __restrict__ Wp1,
    const float* __restrict__ Wp2, const float* __restrict__ Wp3,
    bf16* __restrict__ Xb, bf16* __restrict__ Wob, bf16* __restrict__ Wcat) {
  const int bid = blockIdx.x;
  if (bid < 4096) {
    int i = bid * 256 + threadIdx.x;            // < 1,048,576 = TB*D/4
    float4 v = reinterpret_cast<const float4*>(x)[i];
    bf16* d = Xb + (size_t)i * 4;
    d[0] = __float2bfloat16(v.x); d[1] = __float2bfloat16(v.y);
    d[2] = __float2bfloat16(v.z); d[3] = __float2bfloat16(v.w);
  } else if (bid < 4352) {
    int i = (bid - 4096) * 256 + threadIdx.x;   // < 65,536 = D*D/4
    float4 v = reinterpret_cast<const float4*>(Wo)[i];
    bf16* d = Wob + (size_t)i * 4;
    d[0] = __float2bfloat16(v.x); d[1] = __float2bfloat16(v.y);
    d[2] = __float2bfloat16(v.z); d[3] = __float2bfloat16(v.w);
  } else {
    int i = (bid - 4352) * 256 + threadIdx.x;   // < 1,376,256 = NCOL*512
    int r = i >> 9, k = i & 511;
    float v = 0.f;
    if      (r <  512) v = Wq [(r       ) * D_N + k];
    else if (r < 1024) v = Wk [(r -  512) * D_N + k];
    else if (r < 1536) v = Wv [(r - 1024) * D_N + k];
    else if (r < 2048) v = Wb [(r - 1536) * D_N + k];
    else if (r < 2560) v = Wg [(r - 2048) * D_N + k];
    else if (r < 2592) v = Wp1[(r - 2560) * D_N + k];
    else if (r < 2624) v = Wp2[(r - 2592) * D_N + k];
    else if (r < 2656) v = Wp3[(r - 2624) * D_N + k];
    Wcat[i] = __float2bfloat16(v);
  }
}

// ---------------- bf16 MFMA GEMM: C(M,ldc) = A(M,K) * B(N,K)^T (+bias) ----------------
// 128x128 tile, BK=32, 4 waves; XOR bank-swizzle (both-sides, rule #21) + dbuf with
// __syncthreads only (full fence, race-free). PROVEN round-11: conflicts 2.75M -> 0.
template <typename OutT>
__global__ __launch_bounds__(256) void gemm_bt_bf16(
    const bf16* __restrict__ A, const bf16* __restrict__ Bm,
    OutT* __restrict__ C, const float* __restrict__ bias,
    int K, int ldc) {
  __shared__ __align__(16) bf16 As[2][128 * 32];
  __shared__ __align__(16) bf16 Bs[2][128 * 32];
  const int tid = threadIdx.x;
  const int w = tid >> 6, l = tid & 63;
  const size_t tm = (size_t)blockIdx.x * 128;
  const size_t tn = (size_t)blockIdx.y * 128;
  const int lr = l & 15, lchunk = l >> 4;
  const int wr = (w >> 1) * 64, wc = (w & 1) * 64;
  f32x4 acc[4][4] = {};

  auto stage = [&](int buf, int kt) {
#pragma unroll
    for (int j = 0; j < 2; ++j) {
      int q = (w * 2 + j) * 64 + l;
      int row = q >> 2, cs = q & 3;
      int src = cs ^ ((row >> 1) & 3);
      __builtin_amdgcn_global_load_lds(
          (const __attribute__((address_space(1))) void*)(A + (tm + row) * K + kt + src * 8),
          (__attribute__((address_space(3))) void*)(&As[buf][q * 8]), 16, 0, 0);
      __builtin_amdgcn_global_load_lds(
          (const __attribute__((address_space(1))) void*)(Bm + (tn + row) * K + kt + src * 8),
          (__attribute__((address_space(3))) void*)(&Bs[buf][q * 8]), 16, 0, 0);
    }
  };

  stage(0, 0);
  int cur = 0;
  const int NT = K / 32;
  for (int t = 0; t < NT; ++t) {
    __syncthreads();
    if (t + 1 < NT) stage(cur ^ 1, (t + 1) * 32);
    short8 af[4], bfr[4];
#pragma unroll
    for (int i = 0; i < 4; ++i) {
      int row = wr + i * 16 + lr;
      int cs = lchunk ^ ((row >> 1) & 3);
      af[i] = *reinterpret_cast<const short8*>(&As[cur][row * 32 + cs * 8]);
    }
#pragma unroll
    for (int i = 0; i < 4; ++i) {
      int row = wc + i * 16 + lr;
      int cs = lchunk ^ ((row >> 1) & 3);
      bfr[i] = *reinterpret_cast<const short8*>(&Bs[cur][row * 32 + cs * 8]);
    }
#pragma unroll
    for (int i = 0; i < 4; ++i)
#pragma unroll
      for (int j = 0; j < 4; ++j)
        acc[i][j] = __builtin_amdgcn_mfma_f32_16x16x32_bf16(af[i], bfr[j], acc[i][j], 0, 0, 0);
    cur ^= 1;
  }

  const int oc = l & 15, orow = (l >> 4) * 4;
#pragma unroll
  for (int i = 0; i < 4; ++i)
#pragma unroll
    for (int j = 0; j < 4; ++j) {
      size_t col = tn + wc + j * 16 + oc;
      float bv = bias ? bias[col] : 0.f;
#pragma unroll
      for (int v = 0; v < 4; ++v) {
        size_t row = tm + wr + i * 16 + orow + v;
        float val = acc[i][j][v] + bv;
        if constexpr (__is_same(OutT, bf16))
          C[row * ldc + col] = __float2bfloat16(val);
        else
          C[row * ldc + col] = val;
      }
    }
}

// ---------------- pass 1: per-chunk local scan + decay products ----------------
// 256-thr blocks, bh UNIFORM from blockIdx (scalar bases); c per wave; CLEN preload.
__global__ __launch_bounds__(256) void scan_pass1(
    const unsigned short* __restrict__ proj, const int* __restrict__ term,
    const float* __restrict__ tick, float* __restrict__ Pa, bf16* __restrict__ Ea) {
  const int bh = blockIdx.x >> 3;                               // uniform
  const int c  = ((blockIdx.x & 7) << 2) + (threadIdx.x >> 6);  // per-wave
  const int b = bh >> 3, h = bh & 7;
  const int lane = threadIdx.x & 63;
  const int t0 = c * CLEN;
  const int koff = 512 + h * HD_N + lane;

  unsigned short kv8[CLEN], vv8[CLEN], bl8[CLEN], gl8[CLEN];
  u16x4 p18[CLEN], p38[CLEN];
  int tm8[CLEN];
#pragma unroll
  for (int tt = 0; tt < CLEN; ++tt) {
    const unsigned short* rw = proj + (size_t)((t0 + tt) * B_N + b) * NCOL;
    kv8[tt] = rw[koff];
    vv8[tt] = rw[512 + koff];
    bl8[tt] = rw[1024 + koff];
    gl8[tt] = rw[1536 + koff];
    p18[tt] = *(const u16x4*)(rw + 2560 + h * 4);
    p38[tt] = *(const u16x4*)(rw + 2624 + h * 4);
    tm8[tt] = term[(t0 + tt) * B_N + b];
  }

  float s_st[ETA_N] = {};
  float k_st[ETA_N][R_N] = {};
  float v_st[R_N] = {};
  float Pg[ETA_N] = {1.f, 1.f, 1.f, 1.f};
  float Pb = 1.f;

  float ce[R_N], se[R_N], cw[R_N], sw[R_N];
  const float tk = tick[b];
#pragma unroll
  for (int r = 0; r < R_N; ++r) {
    float w = -3.14159265358979323846f + 2.09439510239319549231f * (float)r;
    float a0 = (tk + (float)(t0 + 1)) * w;
    ce[r] = cosf(a0); se[r] = sinf(a0);
    cw[r] = cosf(w);  sw[r] = sinf(w);
  }

#pragma unroll
  for (int tt = 0; tt < CLEN; ++tt) {
    float k = b2f(kv8[tt]), v = b2f(vv8[tt]);
    float mask  = 1.f - (float)tm8[tt];
    float gamma = sigmoidf_(b2f(gl8[tt]));
    float beta  = sigmoidf_(b2f(bl8[tt]));
    float p1a[4]  = {b2f(p18[tt][0]), b2f(p18[tt][1]), b2f(p18[tt][2]), b2f(p18[tt][3])};
    float sp3a[4] = {sigmoidf_(b2f(p38[tt][0])), sigmoidf_(b2f(p38[tt][1])),
                     sigmoidf_(b2f(p38[tt][2])), sigmoidf_(b2f(p38[tt][3]))};

#pragma unroll
    for (int e = 0; e < ETA_N; ++e) {
      float psi = fmaxf(k * p1a[e], 0.f);
      float gf  = gamma * sp3a[e];
      float gk  = psi * gf;
      float dg  = (1.f - gf) * mask;
      s_st[e] = dg * s_st[e] + gk;
      Pg[e] *= dg;
#pragma unroll
      for (int r = 0; r < R_N; ++r)
        k_st[e][r] = dg * k_st[e][r] + gk * ce[r];
    }
    float gv = v * beta;
    float db = (1.f - beta) * mask;
    Pb *= db;
#pragma unroll
    for (int r = 0; r < R_N; ++r)
      v_st[r] = db * v_st[r] + gv * ce[r];

#pragma unroll
    for (int r = 0; r < R_N; ++r) {
      float c2 = ce[r] * cw[r] - se[r] * sw[r];
      float s2 = se[r] * cw[r] + ce[r] * sw[r];
      ce[r] = c2; se[r] = s2;
    }
  }

  float* pa = Pa + (size_t)(bh * NCHUNK + c) * 320;
#pragma unroll
  for (int e = 0; e < ETA_N; ++e) pa[e * 64 + lane] = Pg[e];
  pa[256 + lane] = Pb;
  bf16* ea = Ea + (size_t)(bh * NCHUNK + c) * 1536;
#pragma unroll
  for (int e = 0; e < ETA_N; ++e) ea[e * 64 + lane] = __float2bfloat16(s_st[e]);
#pragma unroll
  for (int e = 0; e < ETA_N; ++e)
#pragma unroll
    for (int r = 0; r < R_N; ++r)
      ea[256 + (e * 4 + r) * 64 + lane] = __float2bfloat16(k_st[e][r]);
#pragma unroll
  for (int r = 0; r < R_N; ++r) ea[1280 + r * 64 + lane] = __float2bfloat16(v_st[r]);
}

// ---------------- pass 2: elementwise carry combine over chunks (in-place into Ea) ----------------
__global__ __launch_bounds__(256) void scan_pass2(
    const float* __restrict__ Pa, bf16* __restrict__ Ea,
    const float* __restrict__ tkp, const float* __restrict__ tvp,
    const float* __restrict__ sp) {
  const int elem = blockIdx.x * 256 + threadIdx.x;   // 0..1535
  const int bh = blockIdx.y;
  const int b = bh >> 3, h = bh & 7;
  int poff; float cr;
  if (elem < 256) {
    cr = sp[(b * H_N + h) * FEAT_N + elem];
    poff = elem;
  } else if (elem < 1280) {
    int el = elem - 256;
    int e = el >> 8, r = (el >> 6) & 3, d = el & 63;
    cr = tkp[((b * R_N + r) * H_N + h) * FEAT_N + e * 64 + d];
    poff = e * 64 + d;
  } else {
    int el = elem - 1280;
    int r = el >> 6, d = el & 63;
    cr = tvp[((b * R_N + r) * H_N + h) * HD_N + d];
    poff = 256 + d;
  }
  size_t ip = (size_t)(bh * NCHUNK) * 320 + poff;
  size_t ie = (size_t)(bh * NCHUNK) * 1536 + elem;
  float p = Pa[ip];
  float e = __bfloat162float(Ea[ie]);
  for (int c = 0; c < NCHUNK; ++c) {
    float pn = 0.f, en = 0.f;
    if (c + 1 < NCHUNK) { pn = Pa[ip + 320]; en = __bfloat162float(Ea[ie + 1536]); }
    Ea[ie] = __float2bfloat16(cr);
    cr = p * cr + e;
    p = pn; e = en; ip += 320; ie += 1536;
  }
}

// ---------------- pass 3: full per-t compute from correct carries ----------------
// 256-thr blocks, bh uniform, c per wave; CLEN preload.
__global__ __launch_bounds__(256) void scan_pass3(
    const unsigned short* __restrict__ proj, const int* __restrict__ term,
    const bf16* __restrict__ Ea, const float* __restrict__ tick,
    bf16* __restrict__ attn) {
  const int bh = blockIdx.x >> 3;
  const int c  = ((blockIdx.x & 7) << 2) + (threadIdx.x >> 6);
  const int b = bh >> 3, h = bh & 7;
  const int lane = threadIdx.x & 63;
  const int t0 = c * CLEN;
  const int qoff = h * HD_N + lane;

  unsigned short qv8[CLEN], kv8[CLEN], vv8[CLEN], bl8[CLEN], gl8[CLEN];
  u16x4 p18[CLEN], p28[CLEN], p38[CLEN];
  int tm8[CLEN];
#pragma unroll
  for (int tt = 0; tt < CLEN; ++tt) {
    const unsigned short* rw = proj + (size_t)((t0 + tt) * B_N + b) * NCOL;
    qv8[tt] = rw[qoff];
    kv8[tt] = rw[512 + qoff];
    vv8[tt] = rw[1024 + qoff];
    bl8[tt] = rw[1536 + qoff];
    gl8[tt] = rw[2048 + qoff];
    p18[tt] = *(const u16x4*)(rw + 2560 + h * 4);
    p28[tt] = *(const u16x4*)(rw + 2592 + h * 4);
    p38[tt] = *(const u16x4*)(rw + 2624 + h * 4);
    tm8[tt] = term[(t0 + tt) * B_N + b];
  }

  const bf16* cb = Ea + (size_t)(bh * NCHUNK + c) * 1536;
  float s_st[ETA_N], k_st[ETA_N][R_N], v_st[R_N];
#pragma unroll
  for (int e = 0; e < ETA_N; ++e) s_st[e] = __bfloat162float(cb[e * 64 + lane]);
#pragma unroll
  for (int e = 0; e < ETA_N; ++e)
#pragma unroll
    for (int r = 0; r < R_N; ++r)
      k_st[e][r] = __bfloat162float(cb[256 + (e * 4 + r) * 64 + lane]);
#pragma unroll
  for (int r = 0; r < R_N; ++r) v_st[r] = __bfloat162float(cb[1280 + r * 64 + lane]);

  float ce[R_N], se[R_N], cw[R_N], sw[R_N];
  const float tk = tick[b];
#pragma unroll
  for (int r = 0; r < R_N; ++r) {
    float w = -3.14159265358979323846f + 2.09439510239319549231f * (float)r;
    float a0 = (tk + (float)(t0 + 1)) * w;
    ce[r] = cosf(a0); se[r] = sinf(a0);
    cw[r] = cosf(w);  sw[r] = sinf(w);
  }

#pragma unroll
  for (int tt = 0; tt < CLEN; ++tt) {
    float q = b2f(qv8[tt]), k = b2f(kv8[tt]), v = b2f(vv8[tt]);
    float mask  = 1.f - (float)tm8[tt];
    float gamma = sigmoidf_(b2f(gl8[tt]));
    float beta  = sigmoidf_(b2f(bl8[tt]));
    float p1a[4]  = {b2f(p18[tt][0]), b2f(p18[tt][1]), b2f(p18[tt][2]), b2f(p18[tt][3])};
    float p2a[4]  = {b2f(p28[tt][0]), b2f(p28[tt][1]), b2f(p28[tt][2]), b2f(p28[tt][3])};
    float sp3a[4] = {sigmoidf_(b2f(p38[tt][0])), sigmoidf_(b2f(p38[tt][1])),
                     sigmoidf_(b2f(p38[tt][2])), sigmoidf_(b2f(p38[tt][3]))};

    float norm_p = 0.f, kdq0 = 0.f, kdq1 = 0.f, kdq2 = 0.f, kdq3 = 0.f;
#pragma unroll
    for (int e = 0; e < ETA_N; ++e) {
      float psi = fmaxf(k * p1a[e], 0.f);
      float gf  = gamma * sp3a[e];
      float gk  = psi * gf;
      float dg  = (1.f - gf) * mask;
      float phi = fmaxf(q * p2a[e], 0.f);
      s_st[e] = dg * s_st[e] + gk;
      norm_p += s_st[e] * phi;
      k_st[e][0] = dg * k_st[e][0] + gk * ce[0]; kdq0 += k_st[e][0] * phi;
      k_st[e][1] = dg * k_st[e][1] + gk * ce[1]; kdq1 += k_st[e][1] * phi;
      k_st[e][2] = dg * k_st[e][2] + gk * ce[2]; kdq2 += k_st[e][2] * phi;
      k_st[e][3] = dg * k_st[e][3] + gk * ce[3]; kdq3 += k_st[e][3] * phi;
    }
#pragma unroll
    for (int m = 1; m < 64; m <<= 1) {
      norm_p += __shfl_xor(norm_p, m);
      kdq0 += __shfl_xor(kdq0, m);
      kdq1 += __shfl_xor(kdq1, m);
      kdq2 += __shfl_xor(kdq2, m);
      kdq3 += __shfl_xor(kdq3, m);
    }
    float gv = v * beta;
    float db = (1.f - beta) * mask;
    v_st[0] = db * v_st[0] + gv * ce[0];
    v_st[1] = db * v_st[1] + gv * ce[1];
    v_st[2] = db * v_st[2] + gv * ce[2];
    v_st[3] = db * v_st[3] + gv * ce[3];
    float kv = v_st[0] * kdq0 + v_st[1] * kdq1 + v_st[2] * kdq2 + v_st[3] * kdq3;
    float a = kv / (8.f * norm_p + 1e-6f);
    attn[((size_t)((t0 + tt) * B_N + b) * H_N + h) * HD_N + lane] = __float2bfloat16(a);
#pragma unroll
    for (int r = 0; r < R_N; ++r) {
      float c2 = ce[r] * cw[r] - se[r] * sw[r];
      float s2 = se[r] * cw[r] + ce[r] * sw[r];
      ce[r] = c2; se[r] = s2;
    }
  }
}

extern "C" void kernel_launch(void* const* d_in, const int* in_sizes, int n_in,
                              void* d_out, int out_size, void* d_ws, size_t ws_size,
                              hipStream_t stream) {
  const float* x    = (const float*)d_in[0];
  const int*   term = (const int*)  d_in[1];
  const float* tkp  = (const float*)d_in[2];
  const float* tvp  = (const float*)d_in[3];
  const float* sp   = (const float*)d_in[4];
  const float* tick = (const float*)d_in[5];
  const float* Wq   = (const float*)d_in[6];
  const float* Wk   = (const float*)d_in[7];
  const float* Wv   = (const float*)d_in[8];
  const float* Wb   = (const float*)d_in[9];
  const float* Wg   = (const float*)d_in[10];
  const float* Wp1  = (const float*)d_in[11];
  const float* Wp2  = (const float*)d_in[12];
  const float* Wp3  = (const float*)d_in[13];
  const float* Wo   = (const float*)d_in[14];
  const float* bo   = (const float*)d_in[15];
  float* out = (float*)d_out;

  // workspace layout — ZERO OVERLAP, every region disjoint. Total 99,745,792 B.
  char* ws = (char*)d_ws;
  bf16*  projb = (bf16*) (ws);                 // [ 0         , 44,040,192)
  bf16*  Xb    = (bf16*) (ws + 44040192);      // [44,040,192 , 52,428,800)
  bf16*  Wcat  = (bf16*) (ws + 52428800);      // [52,428,800 , 55,181,312)
  bf16*  Wob   = (bf16*) (ws + 55181312);      // [55,181,312 , 55,705,600)
  bf16*  Ea    = (bf16*) (ws + 55705600);      // [55,705,600 , 80,871,424)  25,165,824 B
  float* Pa    = (float*)(ws + 80871424);      // [80,871,424 , 91,357,184)  10,485,760 B (f32)
  bf16*  attn  = (bf16*) (ws + 91357184);      // [91,357,184 , 99,745,792)   8,388,608 B

  prep_all<<<9728, 256, 0, stream>>>(x, Wo, Wq, Wk, Wv, Wb, Wg, Wp1, Wp2, Wp3,
                                     Xb, Wob, Wcat);

  gemm_bt_bf16<bf16><<<dim3(TB_N / 128, NCOL / 128), 256, 0, stream>>>(
      Xb, Wcat, projb, nullptr, D_N, NCOL);

  const unsigned short* proju = (const unsigned short*)projb;
  scan_pass1<<<B_N * H_N * NCHUNK / 4, 256, 0, stream>>>(proju, term, tick, Pa, Ea);
  scan_pass2<<<dim3(6, 256), 256, 0, stream>>>(Pa, Ea, tkp, tvp, sp);
  scan_pass3<<<B_N * H_N * NCHUNK / 4, 256, 0, stream>>>(proju, term, Ea, tick, attn);

  gemm_bt_bf16<float><<<dim3(TB_N / 128, D_N / 128), 256, 0, stream>>>(
      attn, Wob, out, bo, D_N, D_N);
}

// Round 13
// 219.609 us; speedup vs baseline: 1.0558x; 1.0558x over previous
//
#include <hip/hip_runtime.h>
#include <hip/hip_bf16.h>

#define T_N 256
#define B_N 32
#define D_N 512
#define H_N 8
#define HD_N 64
#define ETA_N 4
#define R_N 4
#define FEAT_N 256
#define NCOL 2688            // 5*512 + 3*32 = 2656, padded to 21*128
#define TB_N (T_N * B_N)     // 8192
#define NCHUNK 32
#define CLEN 8               // T / NCHUNK

using bf16 = __hip_bfloat16;
typedef __attribute__((ext_vector_type(8))) short short8;
typedef __attribute__((ext_vector_type(4))) float f32x4;
typedef __attribute__((ext_vector_type(4))) unsigned short u16x4;

__device__ __forceinline__ float sigmoidf_(float x) { return 1.f / (1.f + __expf(-x)); }
__device__ __forceinline__ float b2f(unsigned short u) {
  union { unsigned int i; float f; } x; x.i = ((unsigned int)u) << 16; return x.f;
}

// ---------------- fused prep: cast x -> Xb, cast Wo -> Wob, build Wcat ----------------
__global__ __launch_bounds__(256) void prep_all(
    const float* __restrict__ x, const float* __restrict__ Wo,
    const float* __restrict__ Wq, const float* __restrict__ Wk,
    const float* __restrict__ Wv, const float* __restrict__ Wb,
    const float* __restrict__ Wg, const float* __restrict__ Wp1,
    const float* __restrict__ Wp2, const float* __restrict__ Wp3,
    bf16* __restrict__ Xb, bf16* __restrict__ Wob, bf16* __restrict__ Wcat) {
  const int bid = blockIdx.x;
  if (bid < 4096) {
    int i = bid * 256 + threadIdx.x;            // < 1,048,576 = TB*D/4
    float4 v = reinterpret_cast<const float4*>(x)[i];
    bf16* d = Xb + (size_t)i * 4;
    d[0] = __float2bfloat16(v.x); d[1] = __float2bfloat16(v.y);
    d[2] = __float2bfloat16(v.z); d[3] = __float2bfloat16(v.w);
  } else if (bid < 4352) {
    int i = (bid - 4096) * 256 + threadIdx.x;   // < 65,536 = D*D/4
    float4 v = reinterpret_cast<const float4*>(Wo)[i];
    bf16* d = Wob + (size_t)i * 4;
    d[0] = __float2bfloat16(v.x); d[1] = __float2bfloat16(v.y);
    d[2] = __float2bfloat16(v.z); d[3] = __float2bfloat16(v.w);
  } else {
    int i = (bid - 4352) * 256 + threadIdx.x;   // < 1,376,256 = NCOL*512
    int r = i >> 9, k = i & 511;
    float v = 0.f;
    if      (r <  512) v = Wq [(r       ) * D_N + k];
    else if (r < 1024) v = Wk [(r -  512) * D_N + k];
    else if (r < 1536) v = Wv [(r - 1024) * D_N + k];
    else if (r < 2048) v = Wb [(r - 1536) * D_N + k];
    else if (r < 2560) v = Wg [(r - 2048) * D_N + k];
    else if (r < 2592) v = Wp1[(r - 2560) * D_N + k];
    else if (r < 2624) v = Wp2[(r - 2592) * D_N + k];
    else if (r < 2656) v = Wp3[(r - 2624) * D_N + k];
    Wcat[i] = __float2bfloat16(v);
  }
}

// ---------------- bf16 MFMA GEMM: C(M,ldc) = A(M,K) * B(N,K)^T (+bias) ----------------
// 128x128 tile, BK=32, 4 waves; XOR bank-swizzle (both-sides, rule #21) + dbuf with
// __syncthreads only (full fence, race-free). PROVEN round-11: conflicts 2.75M -> 0.
template <typename OutT>
__global__ __launch_bounds__(256) void gemm_bt_bf16(
    const bf16* __restrict__ A, const bf16* __restrict__ Bm,
    OutT* __restrict__ C, const float* __restrict__ bias,
    int K, int ldc) {
  __shared__ __align__(16) bf16 As[2][128 * 32];
  __shared__ __align__(16) bf16 Bs[2][128 * 32];
  const int tid = threadIdx.x;
  const int w = tid >> 6, l = tid & 63;
  const size_t tm = (size_t)blockIdx.x * 128;
  const size_t tn = (size_t)blockIdx.y * 128;
  const int lr = l & 15, lchunk = l >> 4;
  const int wr = (w >> 1) * 64, wc = (w & 1) * 64;
  f32x4 acc[4][4] = {};

  auto stage = [&](int buf, int kt) {
#pragma unroll
    for (int j = 0; j < 2; ++j) {
      int q = (w * 2 + j) * 64 + l;
      int row = q >> 2, cs = q & 3;
      int src = cs ^ ((row >> 1) & 3);
      __builtin_amdgcn_global_load_lds(
          (const __attribute__((address_space(1))) void*)(A + (tm + row) * K + kt + src * 8),
          (__attribute__((address_space(3))) void*)(&As[buf][q * 8]), 16, 0, 0);
      __builtin_amdgcn_global_load_lds(
          (const __attribute__((address_space(1))) void*)(Bm + (tn + row) * K + kt + src * 8),
          (__attribute__((address_space(3))) void*)(&Bs[buf][q * 8]), 16, 0, 0);
    }
  };

  stage(0, 0);
  int cur = 0;
  const int NT = K / 32;
  for (int t = 0; t < NT; ++t) {
    __syncthreads();
    if (t + 1 < NT) stage(cur ^ 1, (t + 1) * 32);
    short8 af[4], bfr[4];
#pragma unroll
    for (int i = 0; i < 4; ++i) {
      int row = wr + i * 16 + lr;
      int cs = lchunk ^ ((row >> 1) & 3);
      af[i] = *reinterpret_cast<const short8*>(&As[cur][row * 32 + cs * 8]);
    }
#pragma unroll
    for (int i = 0; i < 4; ++i) {
      int row = wc + i * 16 + lr;
      int cs = lchunk ^ ((row >> 1) & 3);
      bfr[i] = *reinterpret_cast<const short8*>(&Bs[cur][row * 32 + cs * 8]);
    }
#pragma unroll
    for (int i = 0; i < 4; ++i)
#pragma unroll
      for (int j = 0; j < 4; ++j)
        acc[i][j] = __builtin_amdgcn_mfma_f32_16x16x32_bf16(af[i], bfr[j], acc[i][j], 0, 0, 0);
    cur ^= 1;
  }

  const int oc = l & 15, orow = (l >> 4) * 4;
#pragma unroll
  for (int i = 0; i < 4; ++i)
#pragma unroll
    for (int j = 0; j < 4; ++j) {
      size_t col = tn + wc + j * 16 + oc;
      float bv = bias ? bias[col] : 0.f;
#pragma unroll
      for (int v = 0; v < 4; ++v) {
        size_t row = tm + wr + i * 16 + orow + v;
        float val = acc[i][j][v] + bv;
        if constexpr (__is_same(OutT, bf16))
          C[row * ldc + col] = __float2bfloat16(val);
        else
          C[row * ldc + col] = val;
      }
    }
}

// ---------------- pass 1: per-chunk local scan + decay products ----------------
// 64-thread blocks (bh,c from blockIdx only -> wave-uniform scalar addressing) +
// full CLEN-deep preload. PROVEN round-10/11 config.
__global__ __launch_bounds__(64) void scan_pass1(
    const unsigned short* __restrict__ proj, const int* __restrict__ term,
    const float* __restrict__ tick, float* __restrict__ Pa, bf16* __restrict__ Ea) {
  const int bc = blockIdx.x;
  const int bh = bc >> 5, c = bc & (NCHUNK - 1);
  const int b = bh >> 3, h = bh & 7;
  const int lane = threadIdx.x;
  const int t0 = c * CLEN;
  const int koff = 512 + h * HD_N + lane;

  unsigned short kv8[CLEN], vv8[CLEN], bl8[CLEN], gl8[CLEN];
  u16x4 p18[CLEN], p38[CLEN];
  int tm8[CLEN];
#pragma unroll
  for (int tt = 0; tt < CLEN; ++tt) {
    const unsigned short* rw = proj + (size_t)((t0 + tt) * B_N + b) * NCOL;
    kv8[tt] = rw[koff];
    vv8[tt] = rw[512 + koff];
    bl8[tt] = rw[1024 + koff];
    gl8[tt] = rw[1536 + koff];
    p18[tt] = *(const u16x4*)(rw + 2560 + h * 4);
    p38[tt] = *(const u16x4*)(rw + 2624 + h * 4);
    tm8[tt] = term[(t0 + tt) * B_N + b];
  }

  float s_st[ETA_N] = {};
  float k_st[ETA_N][R_N] = {};
  float v_st[R_N] = {};
  float Pg[ETA_N] = {1.f, 1.f, 1.f, 1.f};
  float Pb = 1.f;

  float ce[R_N], se[R_N], cw[R_N], sw[R_N];
  const float tk = tick[b];
#pragma unroll
  for (int r = 0; r < R_N; ++r) {
    float w = -3.14159265358979323846f + 2.09439510239319549231f * (float)r;
    float a0 = (tk + (float)(t0 + 1)) * w;
    ce[r] = cosf(a0); se[r] = sinf(a0);
    cw[r] = cosf(w);  sw[r] = sinf(w);
  }

#pragma unroll
  for (int tt = 0; tt < CLEN; ++tt) {
    float k = b2f(kv8[tt]), v = b2f(vv8[tt]);
    float mask  = 1.f - (float)tm8[tt];
    float gamma = sigmoidf_(b2f(gl8[tt]));
    float beta  = sigmoidf_(b2f(bl8[tt]));
    float p1a[4]  = {b2f(p18[tt][0]), b2f(p18[tt][1]), b2f(p18[tt][2]), b2f(p18[tt][3])};
    float sp3a[4] = {sigmoidf_(b2f(p38[tt][0])), sigmoidf_(b2f(p38[tt][1])),
                     sigmoidf_(b2f(p38[tt][2])), sigmoidf_(b2f(p38[tt][3]))};

#pragma unroll
    for (int e = 0; e < ETA_N; ++e) {
      float psi = fmaxf(k * p1a[e], 0.f);
      float gf  = gamma * sp3a[e];
      float gk  = psi * gf;
      float dg  = (1.f - gf) * mask;
      s_st[e] = dg * s_st[e] + gk;
      Pg[e] *= dg;
#pragma unroll
      for (int r = 0; r < R_N; ++r)
        k_st[e][r] = dg * k_st[e][r] + gk * ce[r];
    }
    float gv = v * beta;
    float db = (1.f - beta) * mask;
    Pb *= db;
#pragma unroll
    for (int r = 0; r < R_N; ++r)
      v_st[r] = db * v_st[r] + gv * ce[r];

#pragma unroll
    for (int r = 0; r < R_N; ++r) {
      float c2 = ce[r] * cw[r] - se[r] * sw[r];
      float s2 = se[r] * cw[r] + ce[r] * sw[r];
      ce[r] = c2; se[r] = s2;
    }
  }

  float* pa = Pa + (size_t)(bh * NCHUNK + c) * 320;
#pragma unroll
  for (int e = 0; e < ETA_N; ++e) pa[e * 64 + lane] = Pg[e];
  pa[256 + lane] = Pb;
  bf16* ea = Ea + (size_t)(bh * NCHUNK + c) * 1536;
#pragma unroll
  for (int e = 0; e < ETA_N; ++e) ea[e * 64 + lane] = __float2bfloat16(s_st[e]);
#pragma unroll
  for (int e = 0; e < ETA_N; ++e)
#pragma unroll
    for (int r = 0; r < R_N; ++r)
      ea[256 + (e * 4 + r) * 64 + lane] = __float2bfloat16(k_st[e][r]);
#pragma unroll
  for (int r = 0; r < R_N; ++r) ea[1280 + r * 64 + lane] = __float2bfloat16(v_st[r]);
}

// ---------------- pass 2: elementwise carry combine over chunks (in-place into Ea) ----------------
__global__ __launch_bounds__(256) void scan_pass2(
    const float* __restrict__ Pa, bf16* __restrict__ Ea,
    const float* __restrict__ tkp, const float* __restrict__ tvp,
    const float* __restrict__ sp) {
  const int elem = blockIdx.x * 256 + threadIdx.x;   // 0..1535
  const int bh = blockIdx.y;
  const int b = bh >> 3, h = bh & 7;
  int poff; float cr;
  if (elem < 256) {
    cr = sp[(b * H_N + h) * FEAT_N + elem];
    poff = elem;
  } else if (elem < 1280) {
    int el = elem - 256;
    int e = el >> 8, r = (el >> 6) & 3, d = el & 63;
    cr = tkp[((b * R_N + r) * H_N + h) * FEAT_N + e * 64 + d];
    poff = e * 64 + d;
  } else {
    int el = elem - 1280;
    int r = el >> 6, d = el & 63;
    cr = tvp[((b * R_N + r) * H_N + h) * HD_N + d];
    poff = 256 + d;
  }
  size_t ip = (size_t)(bh * NCHUNK) * 320 + poff;
  size_t ie = (size_t)(bh * NCHUNK) * 1536 + elem;
  float p = Pa[ip];
  float e = __bfloat162float(Ea[ie]);
  for (int c = 0; c < NCHUNK; ++c) {
    float pn = 0.f, en = 0.f;
    if (c + 1 < NCHUNK) { pn = Pa[ip + 320]; en = __bfloat162float(Ea[ie + 1536]); }
    Ea[ie] = __float2bfloat16(cr);
    cr = p * cr + e;
    p = pn; e = en; ip += 320; ie += 1536;
  }
}

// ---------------- pass 3: full per-t compute from correct carries ----------------
// 64-thread blocks + full CLEN-deep preload. PROVEN round-10/11 config.
__global__ __launch_bounds__(64) void scan_pass3(
    const unsigned short* __restrict__ proj, const int* __restrict__ term,
    const bf16* __restrict__ Ea, const float* __restrict__ tick,
    bf16* __restrict__ attn) {
  const int bc = blockIdx.x;
  const int bh = bc >> 5, c = bc & (NCHUNK - 1);
  const int b = bh >> 3, h = bh & 7;
  const int lane = threadIdx.x;
  const int t0 = c * CLEN;
  const int qoff = h * HD_N + lane;

  unsigned short qv8[CLEN], kv8[CLEN], vv8[CLEN], bl8[CLEN], gl8[CLEN];
  u16x4 p18[CLEN], p28[CLEN], p38[CLEN];
  int tm8[CLEN];
#pragma unroll
  for (int tt = 0; tt < CLEN; ++tt) {
    const unsigned short* rw = proj + (size_t)((t0 + tt) * B_N + b) * NCOL;
    qv8[tt] = rw[qoff];
    kv8[tt] = rw[512 + qoff];
    vv8[tt] = rw[1024 + qoff];
    bl8[tt] = rw[1536 + qoff];
    gl8[tt] = rw[2048 + qoff];
    p18[tt] = *(const u16x4*)(rw + 2560 + h * 4);
    p28[tt] = *(const u16x4*)(rw + 2592 + h * 4);
    p38[tt] = *(const u16x4*)(rw + 2624 + h * 4);
    tm8[tt] = term[(t0 + tt) * B_N + b];
  }

  const bf16* cb = Ea + (size_t)(bh * NCHUNK + c) * 1536;
  float s_st[ETA_N], k_st[ETA_N][R_N], v_st[R_N];
#pragma unroll
  for (int e = 0; e < ETA_N; ++e) s_st[e] = __bfloat162float(cb[e * 64 + lane]);
#pragma unroll
  for (int e = 0; e < ETA_N; ++e)
#pragma unroll
    for (int r = 0; r < R_N; ++r)
      k_st[e][r] = __bfloat162float(cb[256 + (e * 4 + r) * 64 + lane]);
#pragma unroll
  for (int r = 0; r < R_N; ++r) v_st[r] = __bfloat162float(cb[1280 + r * 64 + lane]);

  float ce[R_N], se[R_N], cw[R_N], sw[R_N];
  const float tk = tick[b];
#pragma unroll
  for (int r = 0; r < R_N; ++r) {
    float w = -3.14159265358979323846f + 2.09439510239319549231f * (float)r;
    float a0 = (tk + (float)(t0 + 1)) * w;
    ce[r] = cosf(a0); se[r] = sinf(a0);
    cw[r] = cosf(w);  sw[r] = sinf(w);
  }

#pragma unroll
  for (int tt = 0; tt < CLEN; ++tt) {
    float q = b2f(qv8[tt]), k = b2f(kv8[tt]), v = b2f(vv8[tt]);
    float mask  = 1.f - (float)tm8[tt];
    float gamma = sigmoidf_(b2f(gl8[tt]));
    float beta  = sigmoidf_(b2f(bl8[tt]));
    float p1a[4]  = {b2f(p18[tt][0]), b2f(p18[tt][1]), b2f(p18[tt][2]), b2f(p18[tt][3])};
    float p2a[4]  = {b2f(p28[tt][0]), b2f(p28[tt][1]), b2f(p28[tt][2]), b2f(p28[tt][3])};
    float sp3a[4] = {sigmoidf_(b2f(p38[tt][0])), sigmoidf_(b2f(p38[tt][1])),
                     sigmoidf_(b2f(p38[tt][2])), sigmoidf_(b2f(p38[tt][3]))};

    float norm_p = 0.f, kdq0 = 0.f, kdq1 = 0.f, kdq2 = 0.f, kdq3 = 0.f;
#pragma unroll
    for (int e = 0; e < ETA_N; ++e) {
      float psi = fmaxf(k * p1a[e], 0.f);
      float gf  = gamma * sp3a[e];
      float gk  = psi * gf;
      float dg  = (1.f - gf) * mask;
      float phi = fmaxf(q * p2a[e], 0.f);
      s_st[e] = dg * s_st[e] + gk;
      norm_p += s_st[e] * phi;
      k_st[e][0] = dg * k_st[e][0] + gk * ce[0]; kdq0 += k_st[e][0] * phi;
      k_st[e][1] = dg * k_st[e][1] + gk * ce[1]; kdq1 += k_st[e][1] * phi;
      k_st[e][2] = dg * k_st[e][2] + gk * ce[2]; kdq2 += k_st[e][2] * phi;
      k_st[e][3] = dg * k_st[e][3] + gk * ce[3]; kdq3 += k_st[e][3] * phi;
    }
#pragma unroll
    for (int m = 1; m < 64; m <<= 1) {
      norm_p += __shfl_xor(norm_p, m);
      kdq0 += __shfl_xor(kdq0, m);
      kdq1 += __shfl_xor(kdq1, m);
      kdq2 += __shfl_xor(kdq2, m);
      kdq3 += __shfl_xor(kdq3, m);
    }
    float gv = v * beta;
    float db = (1.f - beta) * mask;
    v_st[0] = db * v_st[0] + gv * ce[0];
    v_st[1] = db * v_st[1] + gv * ce[1];
    v_st[2] = db * v_st[2] + gv * ce[2];
    v_st[3] = db * v_st[3] + gv * ce[3];
    float kv = v_st[0] * kdq0 + v_st[1] * kdq1 + v_st[2] * kdq2 + v_st[3] * kdq3;
    float a = kv / (8.f * norm_p + 1e-6f);
    attn[((size_t)((t0 + tt) * B_N + b) * H_N + h) * HD_N + lane] = __float2bfloat16(a);
#pragma unroll
    for (int r = 0; r < R_N; ++r) {
      float c2 = ce[r] * cw[r] - se[r] * sw[r];
      float s2 = se[r] * cw[r] + ce[r] * sw[r];
      ce[r] = c2; se[r] = s2;
    }
  }
}

extern "C" void kernel_launch(void* const* d_in, const int* in_sizes, int n_in,
                              void* d_out, int out_size, void* d_ws, size_t ws_size,
                              hipStream_t stream) {
  const float* x    = (const float*)d_in[0];
  const int*   term = (const int*)  d_in[1];
  const float* tkp  = (const float*)d_in[2];
  const float* tvp  = (const float*)d_in[3];
  const float* sp   = (const float*)d_in[4];
  const float* tick = (const float*)d_in[5];
  const float* Wq   = (const float*)d_in[6];
  const float* Wk   = (const float*)d_in[7];
  const float* Wv   = (const float*)d_in[8];
  const float* Wb   = (const float*)d_in[9];
  const float* Wg   = (const float*)d_in[10];
  const float* Wp1  = (const float*)d_in[11];
  const float* Wp2  = (const float*)d_in[12];
  const float* Wp3  = (const float*)d_in[13];
  const float* Wo   = (const float*)d_in[14];
  const float* bo   = (const float*)d_in[15];
  float* out = (float*)d_out;

  // workspace layout — ZERO OVERLAP, every region disjoint. Total 99,745,792 B.
  char* ws = (char*)d_ws;
  bf16*  projb = (bf16*) (ws);                 // [ 0         , 44,040,192)
  bf16*  Xb    = (bf16*) (ws + 44040192);      // [44,040,192 , 52,428,800)
  bf16*  Wcat  = (bf16*) (ws + 52428800);      // [52,428,800 , 55,181,312)
  bf16*  Wob   = (bf16*) (ws + 55181312);      // [55,181,312 , 55,705,600)
  bf16*  Ea    = (bf16*) (ws + 55705600);      // [55,705,600 , 80,871,424)  25,165,824 B
  float* Pa    = (float*)(ws + 80871424);      // [80,871,424 , 91,357,184)  10,485,760 B (f32)
  bf16*  attn  = (bf16*) (ws + 91357184);      // [91,357,184 , 99,745,792)   8,388,608 B

  prep_all<<<9728, 256, 0, stream>>>(x, Wo, Wq, Wk, Wv, Wb, Wg, Wp1, Wp2, Wp3,
                                     Xb, Wob, Wcat);

  gemm_bt_bf16<bf16><<<dim3(TB_N / 128, NCOL / 128), 256, 0, stream>>>(
      Xb, Wcat, projb, nullptr, D_N, NCOL);

  const unsigned short* proju = (const unsigned short*)projb;
  scan_pass1<<<B_N * H_N * NCHUNK, 64, 0, stream>>>(proju, term, tick, Pa, Ea);
  scan_pass2<<<dim3(6, 256), 256, 0, stream>>>(Pa, Ea, tkp, tvp, sp);
  scan_pass3<<<B_N * H_N * NCHUNK, 64, 0, stream>>>(proju, term, Ea, tick, attn);

  gemm_bt_bf16<float><<<dim3(TB_N / 128, D_N / 128), 256, 0, stream>>>(
      attn, Wob, out, bo, D_N, D_N);
}